// Round 10
// baseline (533.718 us; speedup 1.0000x reference)
//
#include <hip/hip_runtime.h>
#include <hip/hip_fp16.h>

#define NN 50000   // nodes
#define NE 800000  // edges
#define NETOT (NE + NN)  // edges + self loops
#define NH 128     // hidden
#define NG 32      // graphs
#define NL 4       // layers
#define NB 196     // ceil(NN/256)
#define EMBB 782   // emb blocks (64 nodes each) in fused K1
#define HISTB 3125 // ceil(NE/256)
#define PREP4B 256 // 4*WSLOT/256 (W-prep for the 4 layer slots)
#define NTILE 12500 // source-tile width (4 tiles, 1.6 MB of fp8 trunk each)
#define WSLOT (NH * NH)  // 16384 elements per weight slot

typedef __attribute__((ext_vector_type(8))) short bf16x8;
typedef __attribute__((ext_vector_type(4))) float f32x4;
typedef __attribute__((ext_vector_type(2))) float f32x2;

__device__ inline short f2bf(float x) {
  union { float f; unsigned u; } v;
  v.f = x;
  unsigned r = v.u + 0x7FFF + ((v.u >> 16) & 1);
  return (short)(r >> 16);
}
__device__ inline float bf2f(short s) {
  union { unsigned u; float f; } v;
  v.u = ((unsigned)(unsigned short)s) << 16;
  return v.f;
}

// fp8 trunk layout (fragment-major, r1-r3 verified): channel ch = ks*32+quad*8+j
// stored at byte quad*32 + ks*8 + j -> per-lane gather reads its quad's 32
// contiguous bytes (2x uint4) per source row.
// Epilogue writes channels ch = t*16 + quad*4 + r; their dword index is:
__device__ inline int pdw(int t, int quad) {
  return (((2 * t + (quad >> 1)) & 3) << 3) + ((t >> 1) << 1) + (quad & 1);
}

// accumulate one fp8 row slice (2x uint4 = lane's 32 channels) into ag, * w
__device__ inline void fp8row_fma(float (&ag)[4][8], uint4 qa, uint4 qb,
                                  float w) {
  const unsigned dw[8] = {qa.x, qa.y, qa.z, qa.w, qb.x, qb.y, qb.z, qb.w};
#pragma unroll
  for (int ks = 0; ks < 4; ++ks) {
    f32x2 u0 = __builtin_amdgcn_cvt_pk_f32_fp8(dw[2 * ks], 0);
    f32x2 u1 = __builtin_amdgcn_cvt_pk_f32_fp8(dw[2 * ks], 1);
    f32x2 u2 = __builtin_amdgcn_cvt_pk_f32_fp8(dw[2 * ks + 1], 0);
    f32x2 u3 = __builtin_amdgcn_cvt_pk_f32_fp8(dw[2 * ks + 1], 1);
    ag[ks][0] += u0.x * w; ag[ks][1] += u0.y * w;
    ag[ks][2] += u1.x * w; ag[ks][3] += u1.y * w;
    ag[ks][4] += u2.x * w; ag[ks][5] += u2.y * w;
    ag[ks][6] += u3.x * w; ag[ks][7] += u3.y * w;
  }
}

// 256-thread block exclusive scan (wave shuffle + 4-wave combine)
__device__ inline int block_exscan(int v) {
  __shared__ int wsum[4];
  int tid = threadIdx.x, wave = tid >> 6, lane = tid & 63;
  int x = v;
#pragma unroll
  for (int off = 1; off < 64; off <<= 1) {
    int y = __shfl_up(x, off, 64);
    if (lane >= off) x += y;
  }
  if (lane == 63) wsum[wave] = x;
  __syncthreads();
  int wp = 0;
  if (wave > 0) wp += wsum[0];
  if (wave > 1) wp += wsum[1];
  if (wave > 2) wp += wsum[2];
  return wp + x - v;
}

// ---------------- K1 fused: emb GEMM (self-staged W) + hist + layer-W prep ---
__global__ __launch_bounds__(256) void prep_hist_emb_kernel(
    const float* __restrict__ Xf, const float* __restrict__ W_emb,
    const float* __restrict__ W_layers, short* __restrict__ hi,
    short* __restrict__ lo, const int* __restrict__ row,
    const int* __restrict__ col, int* __restrict__ cnt4, int* __restrict__ rank,
    const float* __restrict__ bias, __half* __restrict__ hnew,
    unsigned char* __restrict__ h8) {
  __shared__ short Wh[WSLOT];  // 32 KB (emb blocks only)
  __shared__ short Wl[WSLOT];  // 32 KB
  int tid = threadIdx.x;
  int blk = blockIdx.x;
  if (blk >= EMBB) {
    if (blk < EMBB + HISTB) {
      int e = (blk - EMBB) * 256 + tid;
      if (e < NE) {
        int s = row[e];
        int t = s / NTILE;  // 0..3
        rank[e] = atomicAdd(&cnt4[col[e] * 4 + t], 1);
      }
    } else {
      int i = (blk - EMBB - HISTB) * 256 + tid;
      if (i < 4 * WSLOT) {
        int slot = i >> 14, f = i & (WSLOT - 1);
        int j = f & 7, lane = (f >> 3) & 63, tt = (f >> 9) & 7, ks = f >> 12;
        int n = tt * 16 + (lane & 15);
        int k = ks * 32 + ((lane >> 4) & 3) * 8 + j;
        const float* W = W_layers + (size_t)slot * WSLOT;
        float x = W[n * NH + k];
        short hh = f2bf(x);
        hi[i] = hh;
        lo[i] = f2bf(x - bf2f(hh));
      }
    }
    return;
  }

  // ---- embedding block: self-stage W_emb into LDS in fragment order
#pragma unroll
  for (int i = tid * 8; i < WSLOT; i += 256 * 8) {
    int f = i;
    int lane8 = (f >> 3) & 63, tt = (f >> 9) & 7, ks = f >> 12;
    int n = tt * 16 + (lane8 & 15);
    int k0 = ks * 32 + ((lane8 >> 4) & 3) * 8;
    const float* wr = W_emb + n * NH + k0;
    float4 a0 = *(const float4*)wr;
    float4 a1 = *(const float4*)(wr + 4);
    float wv[8] = {a0.x, a0.y, a0.z, a0.w, a1.x, a1.y, a1.z, a1.w};
    bf16x8 vh, vl;
#pragma unroll
    for (int j = 0; j < 8; ++j) {
      short hh = f2bf(wv[j]);
      vh[j] = hh;
      vl[j] = f2bf(wv[j] - bf2f(hh));
    }
    *(bf16x8*)&Wh[i] = vh;
    *(bf16x8*)&Wl[i] = vl;
  }
  __syncthreads();

  int wave = tid >> 6, lane = tid & 63;
  int quad = lane >> 4, r16 = lane & 15;
  int m0 = blk * 64 + wave * 16;
  if (m0 >= NN) return;
  int mA = m0 + r16;

  f32x4 acc[8];
#pragma unroll
  for (int t = 0; t < 8; ++t) acc[t] = (f32x4){0.f, 0.f, 0.f, 0.f};

#pragma unroll
  for (int ks = 0; ks < 4; ++ks) {
    int klane = ks * 32 + quad * 8;
    const float* xr = Xf + (size_t)mA * NH + klane;
    float4 a0 = *(const float4*)xr;
    float4 a1 = *(const float4*)(xr + 4);
    float af[8] = {a0.x, a0.y, a0.z, a0.w, a1.x, a1.y, a1.z, a1.w};
    bf16x8 xhi, xlo;
#pragma unroll
    for (int j = 0; j < 8; ++j) {
      short h = f2bf(af[j]);
      xhi[j] = h;
      xlo[j] = f2bf(af[j] - bf2f(h));
    }
#pragma unroll
    for (int t = 0; t < 8; ++t) {
      int fidx = ((ks * 8 + t) * 64 + lane) << 3;
      bf16x8 whi = *(const bf16x8*)&Wh[fidx];
      bf16x8 wlo = *(const bf16x8*)&Wl[fidx];
      acc[t] = __builtin_amdgcn_mfma_f32_16x16x32_bf16(whi, xhi, acc[t], 0, 0, 0);
      acc[t] = __builtin_amdgcn_mfma_f32_16x16x32_bf16(whi, xlo, acc[t], 0, 0, 0);
      acc[t] = __builtin_amdgcn_mfma_f32_16x16x32_bf16(wlo, xhi, acc[t], 0, 0, 0);
    }
  }

  int m = m0 + r16;
  int cb = quad * 4;
#pragma unroll
  for (int t = 0; t < 8; ++t) {
    int ch = t * 16 + cb;
    float4 bb = *(const float4*)(bias + ch);
    float o0 = acc[t][0] + bb.x, o1 = acc[t][1] + bb.y;
    float o2 = acc[t][2] + bb.z, o3 = acc[t][3] + bb.w;
    __half2 p01 = __float22half2_rn(make_float2(o0, o1));
    __half2 p23 = __float22half2_rn(make_float2(o2, o3));
    *(uint2*)(hnew + (size_t)m * NH + ch) =
        make_uint2(*(unsigned*)&p01, *(unsigned*)&p23);
    int v = 0;
    v = __builtin_amdgcn_cvt_pk_fp8_f32(o0, o1, v, 0);
    v = __builtin_amdgcn_cvt_pk_fp8_f32(o2, o3, v, 1);
    ((unsigned*)(h8 + (size_t)m * NH))[pdw(t, quad)] = (unsigned)v;
  }
}

// ---------------- scan stage 1: deg' = cnt+1, dis, graph counts, deg hist ----
__global__ __launch_bounds__(256) void scan1_kernel(
    const int* __restrict__ cnt4, int* __restrict__ bsum,
    float* __restrict__ dis, int* __restrict__ deg,
    const int* __restrict__ batch, int* __restrict__ gcnt,
    int* __restrict__ dhist) {
  __shared__ int gbins[NG];
  __shared__ int dbins[64];
  __shared__ int ws[4];
  int tid = threadIdx.x;
  if (tid < NG) gbins[tid] = 0;
  if (tid < 64) dbins[tid] = 0;
  __syncthreads();
  int i = blockIdx.x * 256 + tid;
  int v = 0;
  if (i < NN) {
    int4 c4 = *(const int4*)&cnt4[i * 4];
    v = c4.x + c4.y + c4.z + c4.w + 1;  // + self loop
    deg[i] = v;
    dis[i] = rsqrtf((float)v);
    atomicAdd(&gbins[batch[i]], 1);    // native LDS int atomic
    atomicAdd(&dbins[min(v, 63)], 1);
  }
  int lane = tid & 63;
  int s = v;
#pragma unroll
  for (int off = 32; off; off >>= 1) s += __shfl_down(s, off, 64);
  if (lane == 0) ws[tid >> 6] = s;
  __syncthreads();
  if (tid == 0) bsum[blockIdx.x] = ws[0] + ws[1] + ws[2] + ws[3];
  if (tid < NG && gbins[tid]) atomicAdd(&gcnt[tid], gbins[tid]);
  if (tid < 64 && dbins[tid]) atomicAdd(&dhist[tid], dbins[tid]);
}

// ---------------- scan stage 2+3 fused + self-edge emit + degree-sort perm ---
__global__ __launch_bounds__(256) void scan3b_kernel(
    const int* __restrict__ deg, const int* __restrict__ bsum,
    const float* __restrict__ dis, int* __restrict__ offs,
    int2* __restrict__ csr, const int* __restrict__ dhist,
    int* __restrict__ dcnt, int* __restrict__ perm) {
  __shared__ int ws2[4];
  __shared__ int pbase_s[64];
  int tid = threadIdx.x;
  int b = blockIdx.x;
  int v = (tid < NB && tid < b) ? bsum[tid] : 0;
  int lane = tid & 63;
  int s = v;
#pragma unroll
  for (int off = 32; off; off >>= 1) s += __shfl_down(s, off, 64);
  if (lane == 0) ws2[tid >> 6] = s;
  __syncthreads();
  int bo = ws2[0] + ws2[1] + ws2[2] + ws2[3];
  int i = b * 256 + tid;
  int c = (i < NN) ? deg[i] : 0;
  int ex = block_exscan(c);
  if (i < NN) {
    int o = bo + ex;
    offs[i] = o;
    // self edge at the last slot: x = (src<<6)|tl, y = fp32 weight dis^2
    float dii = dis[i];
    csr[o + c - 1] =
        make_int2((i << 6) | (i & 63), __float_as_int(dii * dii));
  }
  // degree-bin prefix (wave 0 scans the 64-bin histogram redundantly/block)
  if (tid < 64) {
    int x = dhist[tid];
    int incl = x;
#pragma unroll
    for (int off = 1; off < 64; off <<= 1) {
      int y = __shfl_up(incl, off, 64);
      if (tid >= off) incl += y;
    }
    pbase_s[tid] = incl - x;
  }
  __syncthreads();
  if (i < NN) {
    int bin = min(c, 63);
    int r = atomicAdd(&dcnt[bin], 1);
    perm[pbase_s[bin] + r] = i;
  }
}

// ---------------- CSR fill: slot = offs[d] + tile-prefix + rank --------------
__global__ __launch_bounds__(256) void fill_kernel(const int* __restrict__ row,
                                                   const int* __restrict__ col,
                                                   const int* __restrict__ rank,
                                                   const int* __restrict__ cnt4,
                                                   const float* __restrict__ dis,
                                                   const int* __restrict__ offs,
                                                   int2* __restrict__ csr) {
  int e = blockIdx.x * 256 + threadIdx.x;
  if (e < NE) {
    int d = col[e];
    int s = row[e];
    int t = s / NTILE;
    int4 c4 = *(const int4*)&cnt4[d * 4];
    int pre = (t > 0 ? c4.x : 0) + (t > 1 ? c4.y : 0) + (t > 2 ? c4.z : 0);
    int pos = offs[d] + pre + rank[e];
    csr[pos] =
        make_int2((s << 6) | (d & 63), __float_as_int(dis[s] * dis[d]));
  }
}

// ---------------- fused layer: degree-sorted per-lane gather + LDS W ---------
// 512 threads / 128 nodes per block; nodes assigned via degree-sorted perm so
// each wave's 16 nodes have (near-)equal degree -> zero lockstep waste in the
// divergent gather loop. Otherwise the proven r3 structure. LAST layer also
// mean-pools in-block (plain LDS writes + wave-broadcast reduce + done-counter
// finalize) replacing the reduce_pool dispatch.
template <bool LAST>
__global__ __launch_bounds__(512) void layer_fused(
    const unsigned char* __restrict__ h8in, const short* __restrict__ Whi,
    const short* __restrict__ Wlo, const float* __restrict__ bias,
    const __half* __restrict__ hprev, const float* __restrict__ gamma,
    const float* __restrict__ beta, const float* __restrict__ Wout,
    const int* __restrict__ offs, const int2* __restrict__ csr,
    const int* __restrict__ perm, __half* __restrict__ hnew,
    unsigned char* __restrict__ h8out, const int* __restrict__ batch,
    float* __restrict__ gsum, const int* __restrict__ gcnt,
    int* __restrict__ done, float* __restrict__ out) {
  __shared__ short Wh[WSLOT];  // 32 KB
  __shared__ short Wl[WSLOT];  // 32 KB
  __shared__ int2 pool_s[128];
  __shared__ int lastflag_s;
  int tid = threadIdx.x;
#pragma unroll
  for (int i = tid * 8; i < WSLOT; i += 512 * 8) {
    *(bf16x8*)&Wh[i] = *(const bf16x8*)(Whi + i);
    *(bf16x8*)&Wl[i] = *(const bf16x8*)(Wlo + i);
  }
  // no barrier yet: gather overlaps the LDS staging latency

  int wave = tid >> 6, lane = tid & 63;
  int quad = lane >> 4, r16 = lane & 15;
  int m0 = blockIdx.x * 128 + wave * 16;
  bool active = m0 < NN;        // wave-uniform; inactive waves still barrier
  int nd = active ? perm[m0 + r16] : 0;
  int cb = quad * 4;

  // early hprev load: in flight during the whole gather
  uint2 hp[8];
#pragma unroll
  for (int t = 0; t < 8; ++t)
    hp[t] = *(const uint2*)(hprev + (size_t)nd * NH + t * 16 + cb);

  float ag[4][8];
#pragma unroll
  for (int ks = 0; ks < 4; ++ks)
#pragma unroll
    for (int j = 0; j < 8; ++j) ag[ks][j] = 0.f;

  const char* rbase = (const char*)h8in + quad * 32;
  int s0 = offs[nd];
  int e1 = active ? ((nd + 1 < NN) ? offs[nd + 1] : NETOT) : s0;
  int j = s0;
  for (; j + 2 <= e1; j += 2) {
    int2 p0 = csr[j], p1 = csr[j + 1];
    const uint4* r0 = (const uint4*)(rbase + (size_t)(((unsigned)p0.x) >> 6) * NH);
    const uint4* r1 = (const uint4*)(rbase + (size_t)(((unsigned)p1.x) >> 6) * NH);
    uint4 a0 = r0[0], b0 = r0[1];
    uint4 a1 = r1[0], b1 = r1[1];
    fp8row_fma(ag, a0, b0, __int_as_float(p0.y));
    fp8row_fma(ag, a1, b1, __int_as_float(p1.y));
  }
  if (j < e1) {
    int2 p0 = csr[j];
    const uint4* r0 = (const uint4*)(rbase + (size_t)(((unsigned)p0.x) >> 6) * NH);
    uint4 a0 = r0[0], b0 = r0[1];
    fp8row_fma(ag, a0, b0, __int_as_float(p0.y));
  }

  __syncthreads();  // W staging complete; all waves participate

  if (!LAST) {
    if (!active) return;
  }

  float dval = 0.f;
  int gnd = 0;
  if (active) {
    f32x4 acc[8];
#pragma unroll
    for (int t = 0; t < 8; ++t) acc[t] = (f32x4){0.f, 0.f, 0.f, 0.f};

#pragma unroll
    for (int ks = 0; ks < 4; ++ks) {
      bf16x8 xhi, xlo;
#pragma unroll
      for (int q = 0; q < 8; ++q) {
        short hh = f2bf(ag[ks][q]);
        xhi[q] = hh;
        xlo[q] = f2bf(ag[ks][q] - bf2f(hh));
      }
#pragma unroll
      for (int t = 0; t < 8; ++t) {
        int fidx = ((ks * 8 + t) * 64 + lane) << 3;
        bf16x8 whi = *(const bf16x8*)&Wh[fidx];
        bf16x8 wlo = *(const bf16x8*)&Wl[fidx];
        acc[t] = __builtin_amdgcn_mfma_f32_16x16x32_bf16(whi, xhi, acc[t], 0, 0, 0);
        acc[t] = __builtin_amdgcn_mfma_f32_16x16x32_bf16(whi, xlo, acc[t], 0, 0, 0);
        acc[t] = __builtin_amdgcn_mfma_f32_16x16x32_bf16(wlo, xhi, acc[t], 0, 0, 0);
      }
    }

    // ---- epilogue: lane owns node m = nd, channels ch = t*16 + quad*4 + r
    int m = nd;
    float vv[8][4];
    float s = 0.f, s2 = 0.f;
#pragma unroll
    for (int t = 0; t < 8; ++t) {
      int ch = t * 16 + cb;
      float4 bb = *(const float4*)(bias + ch);
      float2 h01 = __half22float2(*(__half2*)&hp[t].x);
      float2 h23 = __half22float2(*(__half2*)&hp[t].y);
      float hv[4] = {h01.x, h01.y, h23.x, h23.y};
      float bb4[4] = {bb.x, bb.y, bb.z, bb.w};
#pragma unroll
      for (int r = 0; r < 4; ++r) {
        float z = fmaxf(acc[t][r] + bb4[r], 0.f);
        float val = hv[r] + z;
        vv[t][r] = val;
        s += val;
        s2 += val * val;
      }
    }
    s += __shfl_xor(s, 16, 64);
    s += __shfl_xor(s, 32, 64);
    s2 += __shfl_xor(s2, 16, 64);
    s2 += __shfl_xor(s2, 32, 64);
    float mean = s * (1.f / 128.f);
    float var = fmaxf(s2 * (1.f / 128.f) - mean * mean, 0.f);
    float inv = rsqrtf(var + 1e-5f);
    float d = 0.f;
#pragma unroll
    for (int t = 0; t < 8; ++t) {
      int ch = t * 16 + cb;
      float4 gv = *(const float4*)(gamma + ch);
      float4 bt = *(const float4*)(beta + ch);
      float o0 = (vv[t][0] - mean) * inv * gv.x + bt.x;
      float o1 = (vv[t][1] - mean) * inv * gv.y + bt.y;
      float o2 = (vv[t][2] - mean) * inv * gv.z + bt.z;
      float o3 = (vv[t][3] - mean) * inv * gv.w + bt.w;
      if (!LAST) {
        __half2 p01 = __float22half2_rn(make_float2(o0, o1));
        __half2 p23 = __float22half2_rn(make_float2(o2, o3));
        *(uint2*)(hnew + (size_t)m * NH + ch) =
            make_uint2(*(unsigned*)&p01, *(unsigned*)&p23);
        int pv = 0;
        pv = __builtin_amdgcn_cvt_pk_fp8_f32(o0, o1, pv, 0);
        pv = __builtin_amdgcn_cvt_pk_fp8_f32(o2, o3, pv, 1);
        ((unsigned*)(h8out + (size_t)m * NH))[pdw(t, quad)] = (unsigned)pv;
      } else {
        float4 wv = *(const float4*)(Wout + ch);
        d += o0 * wv.x + o1 * wv.y + o2 * wv.z + o3 * wv.w;
      }
    }
    if (LAST) {
      d += __shfl_xor(d, 16, 64);
      d += __shfl_xor(d, 32, 64);
      dval = d;
      gnd = batch[m];
    }
  }

  if (LAST) {
    // in-block mean-pool: plain LDS writes, wave-0 broadcast reduce
    if (lane < 16)
      pool_s[wave * 16 + r16] =
          make_int2(active ? gnd : 0, __float_as_int(active ? dval : 0.f));
    __syncthreads();
    if (tid < 32) {
      float acc = 0.f;
#pragma unroll 8
      for (int k = 0; k < 128; ++k) {
        int2 e = pool_s[k];  // broadcast read
        if (e.x == tid) acc += __int_as_float(e.y);
      }
      atomicAdd(&gsum[tid], acc);
    }
    __threadfence();
    if (tid == 0) lastflag_s = (atomicAdd(done, 1) == (int)gridDim.x - 1);
    __syncthreads();
    if (lastflag_s && tid < NG) {
      float sv = atomicAdd(&gsum[tid], 0.f);
      out[tid] = sv / fmaxf((float)gcnt[tid], 1.0f);
    }
  }
}

extern "C" void kernel_launch(void* const* d_in, const int* in_sizes, int n_in,
                              void* d_out, int out_size, void* d_ws, size_t ws_size,
                              hipStream_t stream) {
  const float* x = (const float*)d_in[0];
  const int* eidx = (const int*)d_in[1];
  const int* batch = (const int*)d_in[2];
  const float* W_emb = (const float*)d_in[3];
  const float* b_emb = (const float*)d_in[4];
  const float* W_layers = (const float*)d_in[5];
  const float* b_layers = (const float*)d_in[6];
  const float* ln_gamma = (const float*)d_in[7];
  const float* ln_beta = (const float*)d_in[8];
  const float* W_out = (const float*)d_in[9];
  float* out = (float*)d_out;

  char* ws = (char*)d_ws;
  unsigned char* h8a = (unsigned char*)ws; ws += (size_t)NN * NH;  // fp8 trunk A
  unsigned char* h8b = (unsigned char*)ws; ws += (size_t)NN * NH;  // fp8 trunk B
  __half* h = (__half*)ws;      ws += (size_t)NN * NH * 2;         // fp16 trunk
  short* Whi = (short*)ws;      ws += (size_t)4 * WSLOT * 2;
  short* Wlo = (short*)ws;      ws += (size_t)4 * WSLOT * 2;
  float* dis = (float*)ws;      ws += (size_t)NN * 4;
  int2* csr = (int2*)ws;        ws += (size_t)NETOT * 8;
  int* rank = (int*)ws;         ws += (size_t)NE * 4;
  int* offs = (int*)ws;         ws += (size_t)NN * 4;
  int* deg = (int*)ws;          ws += (size_t)NN * 4;
  int* perm = (int*)ws;         ws += (size_t)NN * 4;
  int* bsum = (int*)ws;         ws += (size_t)NB * 4;
  char* zero_base = ws;
  int* cnt4 = (int*)ws;         ws += (size_t)NN * 16;
  float* gsum = (float*)ws;     ws += (size_t)NG * 4;
  int* gcnt = (int*)ws;         ws += (size_t)NG * 4;
  int* dhist = (int*)ws;        ws += 64 * 4;
  int* dcnt = (int*)ws;         ws += 64 * 4;
  int* done = (int*)ws;         ws += 64;
  size_t zero_bytes = (size_t)(ws - zero_base);
  hipMemsetAsync(zero_base, 0, zero_bytes, stream);

  const int* erow = eidx;        // edge_index[0] = sources
  const int* ecol = eidx + NE;   // edge_index[1] = targets

  // K1: emb (self-staged W_emb) + hist + layer-W prep, one dispatch
  prep_hist_emb_kernel<<<EMBB + HISTB + PREP4B, 256, 0, stream>>>(
      x, W_emb, W_layers, Whi, Wlo, erow, ecol, cnt4, rank, b_emb, h, h8a);
  scan1_kernel<<<NB, 256, 0, stream>>>(cnt4, bsum, dis, deg, batch, gcnt,
                                       dhist);
  scan3b_kernel<<<NB, 256, 0, stream>>>(deg, bsum, dis, offs, csr, dhist, dcnt,
                                        perm);
  fill_kernel<<<HISTB, 256, 0, stream>>>(erow, ecol, rank, cnt4, dis, offs, csr);

  int gblk = (NN + 127) / 128;
  for (int l = 0; l < NL; ++l) {
    const short* wh = Whi + (size_t)l * WSLOT;
    const short* wl = Wlo + (size_t)l * WSLOT;
    const float* bl = b_layers + (size_t)l * NH;
    const float* gl = ln_gamma + (size_t)l * NH;
    const float* be = ln_beta + (size_t)l * NH;
    const unsigned char* hin = (l & 1) ? h8b : h8a;
    unsigned char* hout = (l & 1) ? h8a : h8b;
    if (l == NL - 1)
      layer_fused<true><<<gblk, 512, 0, stream>>>(
          hin, wh, wl, bl, h, gl, be, W_out, offs, csr, perm, h, nullptr,
          batch, gsum, gcnt, done, out);
    else
      layer_fused<false><<<gblk, 512, 0, stream>>>(
          hin, wh, wl, bl, h, gl, be, nullptr, offs, csr, perm, h, hout,
          batch, gsum, gcnt, done, out);
  }
}

// Round 11
// 392.078 us; speedup vs baseline: 1.3613x; 1.3613x over previous
//
#include <hip/hip_runtime.h>
#include <hip/hip_fp16.h>

#define NN 50000   // nodes
#define NE 800000  // edges
#define NETOT (NE + NN)  // edges + self loops
#define NH 128     // hidden
#define NG 32      // graphs
#define NL 4       // layers
#define NB 196     // ceil(NN/256)
#define EMBB 782   // emb blocks (64 nodes each) in fused K1
#define HISTB 3125 // ceil(NE/256)
#define PREP4B 256 // 4*WSLOT/256 (W-prep for the 4 layer slots)
#define NTILE 12500 // source-tile width (4 tiles, 1.6 MB of fp8 trunk each)
#define WSLOT (NH * NH)  // 16384 elements per weight slot

typedef __attribute__((ext_vector_type(8))) short bf16x8;
typedef __attribute__((ext_vector_type(4))) float f32x4;
typedef __attribute__((ext_vector_type(2))) float f32x2;

__device__ inline short f2bf(float x) {
  union { float f; unsigned u; } v;
  v.f = x;
  unsigned r = v.u + 0x7FFF + ((v.u >> 16) & 1);
  return (short)(r >> 16);
}
__device__ inline float bf2f(short s) {
  union { unsigned u; float f; } v;
  v.u = ((unsigned)(unsigned short)s) << 16;
  return v.f;
}

// fp8 trunk layout (fragment-major, r1-r3 verified): channel ch = ks*32+quad*8+j
// stored at byte quad*32 + ks*8 + j -> per-lane gather reads its quad's 32
// contiguous bytes (2x uint4) per source row.
// Epilogue writes channels ch = t*16 + quad*4 + r; their dword index is:
__device__ inline int pdw(int t, int quad) {
  return (((2 * t + (quad >> 1)) & 3) << 3) + ((t >> 1) << 1) + (quad & 1);
}

// accumulate one fp8 row slice (2x uint4 = lane's 32 channels) into ag, * w
__device__ inline void fp8row_fma(float (&ag)[4][8], uint4 qa, uint4 qb,
                                  float w) {
  const unsigned dw[8] = {qa.x, qa.y, qa.z, qa.w, qb.x, qb.y, qb.z, qb.w};
#pragma unroll
  for (int ks = 0; ks < 4; ++ks) {
    f32x2 u0 = __builtin_amdgcn_cvt_pk_f32_fp8(dw[2 * ks], 0);
    f32x2 u1 = __builtin_amdgcn_cvt_pk_f32_fp8(dw[2 * ks], 1);
    f32x2 u2 = __builtin_amdgcn_cvt_pk_f32_fp8(dw[2 * ks + 1], 0);
    f32x2 u3 = __builtin_amdgcn_cvt_pk_f32_fp8(dw[2 * ks + 1], 1);
    ag[ks][0] += u0.x * w; ag[ks][1] += u0.y * w;
    ag[ks][2] += u1.x * w; ag[ks][3] += u1.y * w;
    ag[ks][4] += u2.x * w; ag[ks][5] += u2.y * w;
    ag[ks][6] += u3.x * w; ag[ks][7] += u3.y * w;
  }
}

// 256-thread block exclusive scan (wave shuffle + 4-wave combine)
__device__ inline int block_exscan(int v) {
  __shared__ int wsum[4];
  int tid = threadIdx.x, wave = tid >> 6, lane = tid & 63;
  int x = v;
#pragma unroll
  for (int off = 1; off < 64; off <<= 1) {
    int y = __shfl_up(x, off, 64);
    if (lane >= off) x += y;
  }
  if (lane == 63) wsum[wave] = x;
  __syncthreads();
  int wp = 0;
  if (wave > 0) wp += wsum[0];
  if (wave > 1) wp += wsum[1];
  if (wave > 2) wp += wsum[2];
  return wp + x - v;
}

// ---------------- K1 fused: emb GEMM (self-staged W) + hist + layer-W prep ---
__global__ __launch_bounds__(256) void prep_hist_emb_kernel(
    const float* __restrict__ Xf, const float* __restrict__ W_emb,
    const float* __restrict__ W_layers, short* __restrict__ hi,
    short* __restrict__ lo, const int* __restrict__ row,
    const int* __restrict__ col, int* __restrict__ cnt4, int* __restrict__ rank,
    const float* __restrict__ bias, __half* __restrict__ hnew,
    unsigned char* __restrict__ h8) {
  __shared__ short Wh[WSLOT];  // 32 KB (emb blocks only)
  __shared__ short Wl[WSLOT];  // 32 KB
  int tid = threadIdx.x;
  int blk = blockIdx.x;
  if (blk >= EMBB) {
    if (blk < EMBB + HISTB) {
      int e = (blk - EMBB) * 256 + tid;
      if (e < NE) {
        int s = row[e];
        int t = s / NTILE;  // 0..3
        rank[e] = atomicAdd(&cnt4[col[e] * 4 + t], 1);
      }
    } else {
      int i = (blk - EMBB - HISTB) * 256 + tid;
      if (i < 4 * WSLOT) {
        int slot = i >> 14, f = i & (WSLOT - 1);
        int j = f & 7, lane = (f >> 3) & 63, tt = (f >> 9) & 7, ks = f >> 12;
        int n = tt * 16 + (lane & 15);
        int k = ks * 32 + ((lane >> 4) & 3) * 8 + j;
        const float* W = W_layers + (size_t)slot * WSLOT;
        float x = W[n * NH + k];
        short hh = f2bf(x);
        hi[i] = hh;
        lo[i] = f2bf(x - bf2f(hh));
      }
    }
    return;
  }

  // ---- embedding block: self-stage W_emb into LDS in fragment order
#pragma unroll
  for (int i = tid * 8; i < WSLOT; i += 256 * 8) {
    int f = i;
    int lane8 = (f >> 3) & 63, tt = (f >> 9) & 7, ks = f >> 12;
    int n = tt * 16 + (lane8 & 15);
    int k0 = ks * 32 + ((lane8 >> 4) & 3) * 8;
    const float* wr = W_emb + n * NH + k0;
    float4 a0 = *(const float4*)wr;
    float4 a1 = *(const float4*)(wr + 4);
    float wv[8] = {a0.x, a0.y, a0.z, a0.w, a1.x, a1.y, a1.z, a1.w};
    bf16x8 vh, vl;
#pragma unroll
    for (int j = 0; j < 8; ++j) {
      short hh = f2bf(wv[j]);
      vh[j] = hh;
      vl[j] = f2bf(wv[j] - bf2f(hh));
    }
    *(bf16x8*)&Wh[i] = vh;
    *(bf16x8*)&Wl[i] = vl;
  }
  __syncthreads();

  int wave = tid >> 6, lane = tid & 63;
  int quad = lane >> 4, r16 = lane & 15;
  int m0 = blk * 64 + wave * 16;
  if (m0 >= NN) return;
  int mA = m0 + r16;

  f32x4 acc[8];
#pragma unroll
  for (int t = 0; t < 8; ++t) acc[t] = (f32x4){0.f, 0.f, 0.f, 0.f};

#pragma unroll
  for (int ks = 0; ks < 4; ++ks) {
    int klane = ks * 32 + quad * 8;
    const float* xr = Xf + (size_t)mA * NH + klane;
    float4 a0 = *(const float4*)xr;
    float4 a1 = *(const float4*)(xr + 4);
    float af[8] = {a0.x, a0.y, a0.z, a0.w, a1.x, a1.y, a1.z, a1.w};
    bf16x8 xhi, xlo;
#pragma unroll
    for (int j = 0; j < 8; ++j) {
      short h = f2bf(af[j]);
      xhi[j] = h;
      xlo[j] = f2bf(af[j] - bf2f(h));
    }
#pragma unroll
    for (int t = 0; t < 8; ++t) {
      int fidx = ((ks * 8 + t) * 64 + lane) << 3;
      bf16x8 whi = *(const bf16x8*)&Wh[fidx];
      bf16x8 wlo = *(const bf16x8*)&Wl[fidx];
      acc[t] = __builtin_amdgcn_mfma_f32_16x16x32_bf16(whi, xhi, acc[t], 0, 0, 0);
      acc[t] = __builtin_amdgcn_mfma_f32_16x16x32_bf16(whi, xlo, acc[t], 0, 0, 0);
      acc[t] = __builtin_amdgcn_mfma_f32_16x16x32_bf16(wlo, xhi, acc[t], 0, 0, 0);
    }
  }

  int m = m0 + r16;
  int cb = quad * 4;
#pragma unroll
  for (int t = 0; t < 8; ++t) {
    int ch = t * 16 + cb;
    float4 bb = *(const float4*)(bias + ch);
    float o0 = acc[t][0] + bb.x, o1 = acc[t][1] + bb.y;
    float o2 = acc[t][2] + bb.z, o3 = acc[t][3] + bb.w;
    __half2 p01 = __float22half2_rn(make_float2(o0, o1));
    __half2 p23 = __float22half2_rn(make_float2(o2, o3));
    *(uint2*)(hnew + (size_t)m * NH + ch) =
        make_uint2(*(unsigned*)&p01, *(unsigned*)&p23);
    int v = 0;
    v = __builtin_amdgcn_cvt_pk_fp8_f32(o0, o1, v, 0);
    v = __builtin_amdgcn_cvt_pk_fp8_f32(o2, o3, v, 1);
    ((unsigned*)(h8 + (size_t)m * NH))[pdw(t, quad)] = (unsigned)v;
  }
}

// ---------------- scan stage 1: deg' = cnt+1, dis, per-block histograms ------
// NO global atomics: per-block graph counts and degree-bin counts are written
// as plain arrays (gcnt_part[b][32], bcnt[b][64]) and combined downstream.
__global__ __launch_bounds__(256) void scan1_kernel(
    const int* __restrict__ cnt4, int* __restrict__ bsum,
    float* __restrict__ dis, int* __restrict__ deg,
    const int* __restrict__ batch, int* __restrict__ gcnt_part,
    int* __restrict__ bcnt) {
  __shared__ int gbins[NG];
  __shared__ int dbins[64];
  __shared__ int ws[4];
  int tid = threadIdx.x;
  if (tid < NG) gbins[tid] = 0;
  if (tid < 64) dbins[tid] = 0;
  __syncthreads();
  int i = blockIdx.x * 256 + tid;
  int v = 0;
  if (i < NN) {
    int4 c4 = *(const int4*)&cnt4[i * 4];
    v = c4.x + c4.y + c4.z + c4.w + 1;  // + self loop
    deg[i] = v;
    dis[i] = rsqrtf((float)v);
    atomicAdd(&gbins[batch[i]], 1);    // native LDS int atomic
    atomicAdd(&dbins[min(v, 63)], 1);
  }
  int lane = tid & 63;
  int s = v;
#pragma unroll
  for (int off = 32; off; off >>= 1) s += __shfl_down(s, off, 64);
  if (lane == 0) ws[tid >> 6] = s;
  __syncthreads();
  if (tid == 0) bsum[blockIdx.x] = ws[0] + ws[1] + ws[2] + ws[3];
  if (tid < NG) gcnt_part[blockIdx.x * NG + tid] = gbins[tid];
  if (tid < 64) bcnt[blockIdx.x * 64 + tid] = dbins[tid];
}

// ---------------- scan stage 2+3 fused + self-edge emit + degree-sort perm ---
// perm rank = pbase[bin] (prefix over bins of global totals)
//           + cs_lt[bin]  (this bin's count in earlier blocks)
//           + local rank  (native LDS int atomic, per-block)
// -> bijection, zero global atomics.
__global__ __launch_bounds__(256) void scan3b_kernel(
    const int* __restrict__ deg, const int* __restrict__ bsum,
    const float* __restrict__ dis, int* __restrict__ offs,
    int2* __restrict__ csr, const int* __restrict__ bcnt,
    int* __restrict__ perm) {
  __shared__ int ws2[4];
  __shared__ int base_s[64];
  __shared__ int lrk[64];
  int tid = threadIdx.x;
  int b = blockIdx.x;

  // cross-block bin sums (issue early; L2-hot 50 KB)
  int cs_all = 0, cs_lt = 0;
  if (tid < 64) {
    for (int b2 = 0; b2 < NB; ++b2) {
      int c2 = bcnt[b2 * 64 + tid];
      cs_all += c2;
      if (b2 < b) cs_lt += c2;
    }
    lrk[tid] = 0;
  }

  int v = (tid < NB && tid < b) ? bsum[tid] : 0;
  int lane = tid & 63;
  int s = v;
#pragma unroll
  for (int off = 32; off; off >>= 1) s += __shfl_down(s, off, 64);
  if (lane == 0) ws2[tid >> 6] = s;
  __syncthreads();
  int bo = ws2[0] + ws2[1] + ws2[2] + ws2[3];
  int i = b * 256 + tid;
  int c = (i < NN) ? deg[i] : 0;
  int ex = block_exscan(c);  // contains its own __syncthreads
  if (i < NN) {
    int o = bo + ex;
    offs[i] = o;
    // self edge at the last slot: x = (src<<6)|tl, y = fp32 weight dis^2
    float dii = dis[i];
    csr[o + c - 1] =
        make_int2((i << 6) | (i & 63), __float_as_int(dii * dii));
  }
  // exclusive prefix of cs_all over the 64 bins (wave 0)
  if (tid < 64) {
    int incl = cs_all;
#pragma unroll
    for (int off = 1; off < 64; off <<= 1) {
      int y = __shfl_up(incl, off, 64);
      if (tid >= off) incl += y;
    }
    base_s[tid] = (incl - cs_all) + cs_lt;
  }
  __syncthreads();
  if (i < NN) {
    int bin = min(c, 63);
    int r = atomicAdd(&lrk[bin], 1);  // native LDS int atomic
    perm[base_s[bin] + r] = i;
  }
}

// ---------------- CSR fill: slot = offs[d] + tile-prefix + rank --------------
__global__ __launch_bounds__(256) void fill_kernel(const int* __restrict__ row,
                                                   const int* __restrict__ col,
                                                   const int* __restrict__ rank,
                                                   const int* __restrict__ cnt4,
                                                   const float* __restrict__ dis,
                                                   const int* __restrict__ offs,
                                                   int2* __restrict__ csr) {
  int e = blockIdx.x * 256 + threadIdx.x;
  if (e < NE) {
    int d = col[e];
    int s = row[e];
    int t = s / NTILE;
    int4 c4 = *(const int4*)&cnt4[d * 4];
    int pre = (t > 0 ? c4.x : 0) + (t > 1 ? c4.y : 0) + (t > 2 ? c4.z : 0);
    int pos = offs[d] + pre + rank[e];
    csr[pos] =
        make_int2((s << 6) | (d & 63), __float_as_int(dis[s] * dis[d]));
  }
}

// ---------------- fused layer: degree-sorted per-lane gather + LDS W ---------
// 512 threads / 128 nodes per block; nodes assigned via degree-sorted perm so
// each wave's 16 nodes have (near-)equal degree -> zero lockstep waste in the
// divergent gather loop. Otherwise the proven r3 structure. LAST layer also
// mean-pools in-block (plain LDS writes + wave-broadcast reduce + done-counter
// finalize) replacing the reduce_pool dispatch.
template <bool LAST>
__global__ __launch_bounds__(512) void layer_fused(
    const unsigned char* __restrict__ h8in, const short* __restrict__ Whi,
    const short* __restrict__ Wlo, const float* __restrict__ bias,
    const __half* __restrict__ hprev, const float* __restrict__ gamma,
    const float* __restrict__ beta, const float* __restrict__ Wout,
    const int* __restrict__ offs, const int2* __restrict__ csr,
    const int* __restrict__ perm, __half* __restrict__ hnew,
    unsigned char* __restrict__ h8out, const int* __restrict__ batch,
    float* __restrict__ gsum, const int* __restrict__ gcnt_part,
    int* __restrict__ done, float* __restrict__ out) {
  __shared__ short Wh[WSLOT];  // 32 KB
  __shared__ short Wl[WSLOT];  // 32 KB
  __shared__ int2 pool_s[128];
  __shared__ int lastflag_s;
  int tid = threadIdx.x;
#pragma unroll
  for (int i = tid * 8; i < WSLOT; i += 512 * 8) {
    *(bf16x8*)&Wh[i] = *(const bf16x8*)(Whi + i);
    *(bf16x8*)&Wl[i] = *(const bf16x8*)(Wlo + i);
  }
  // no barrier yet: gather overlaps the LDS staging latency

  int wave = tid >> 6, lane = tid & 63;
  int quad = lane >> 4, r16 = lane & 15;
  int m0 = blockIdx.x * 128 + wave * 16;
  bool active = m0 < NN;        // wave-uniform; inactive waves still barrier
  int nd = active ? perm[m0 + r16] : 0;
  int cb = quad * 4;

  // early hprev load: in flight during the whole gather
  uint2 hp[8];
#pragma unroll
  for (int t = 0; t < 8; ++t)
    hp[t] = *(const uint2*)(hprev + (size_t)nd * NH + t * 16 + cb);

  float ag[4][8];
#pragma unroll
  for (int ks = 0; ks < 4; ++ks)
#pragma unroll
    for (int j = 0; j < 8; ++j) ag[ks][j] = 0.f;

  const char* rbase = (const char*)h8in + quad * 32;
  int s0 = offs[nd];
  int e1 = active ? ((nd + 1 < NN) ? offs[nd + 1] : NETOT) : s0;
  int j = s0;
  for (; j + 2 <= e1; j += 2) {
    int2 p0 = csr[j], p1 = csr[j + 1];
    const uint4* r0 = (const uint4*)(rbase + (size_t)(((unsigned)p0.x) >> 6) * NH);
    const uint4* r1 = (const uint4*)(rbase + (size_t)(((unsigned)p1.x) >> 6) * NH);
    uint4 a0 = r0[0], b0 = r0[1];
    uint4 a1 = r1[0], b1 = r1[1];
    fp8row_fma(ag, a0, b0, __int_as_float(p0.y));
    fp8row_fma(ag, a1, b1, __int_as_float(p1.y));
  }
  if (j < e1) {
    int2 p0 = csr[j];
    const uint4* r0 = (const uint4*)(rbase + (size_t)(((unsigned)p0.x) >> 6) * NH);
    uint4 a0 = r0[0], b0 = r0[1];
    fp8row_fma(ag, a0, b0, __int_as_float(p0.y));
  }

  __syncthreads();  // W staging complete; all waves participate

  if (!LAST) {
    if (!active) return;
  }

  float dval = 0.f;
  int gnd = 0;
  if (active) {
    f32x4 acc[8];
#pragma unroll
    for (int t = 0; t < 8; ++t) acc[t] = (f32x4){0.f, 0.f, 0.f, 0.f};

#pragma unroll
    for (int ks = 0; ks < 4; ++ks) {
      bf16x8 xhi, xlo;
#pragma unroll
      for (int q = 0; q < 8; ++q) {
        short hh = f2bf(ag[ks][q]);
        xhi[q] = hh;
        xlo[q] = f2bf(ag[ks][q] - bf2f(hh));
      }
#pragma unroll
      for (int t = 0; t < 8; ++t) {
        int fidx = ((ks * 8 + t) * 64 + lane) << 3;
        bf16x8 whi = *(const bf16x8*)&Wh[fidx];
        bf16x8 wlo = *(const bf16x8*)&Wl[fidx];
        acc[t] = __builtin_amdgcn_mfma_f32_16x16x32_bf16(whi, xhi, acc[t], 0, 0, 0);
        acc[t] = __builtin_amdgcn_mfma_f32_16x16x32_bf16(whi, xlo, acc[t], 0, 0, 0);
        acc[t] = __builtin_amdgcn_mfma_f32_16x16x32_bf16(wlo, xhi, acc[t], 0, 0, 0);
      }
    }

    // ---- epilogue: lane owns node m = nd, channels ch = t*16 + quad*4 + r
    int m = nd;
    float vv[8][4];
    float s = 0.f, s2 = 0.f;
#pragma unroll
    for (int t = 0; t < 8; ++t) {
      int ch = t * 16 + cb;
      float4 bb = *(const float4*)(bias + ch);
      float2 h01 = __half22float2(*(__half2*)&hp[t].x);
      float2 h23 = __half22float2(*(__half2*)&hp[t].y);
      float hv[4] = {h01.x, h01.y, h23.x, h23.y};
      float bb4[4] = {bb.x, bb.y, bb.z, bb.w};
#pragma unroll
      for (int r = 0; r < 4; ++r) {
        float z = fmaxf(acc[t][r] + bb4[r], 0.f);
        float val = hv[r] + z;
        vv[t][r] = val;
        s += val;
        s2 += val * val;
      }
    }
    s += __shfl_xor(s, 16, 64);
    s += __shfl_xor(s, 32, 64);
    s2 += __shfl_xor(s2, 16, 64);
    s2 += __shfl_xor(s2, 32, 64);
    float mean = s * (1.f / 128.f);
    float var = fmaxf(s2 * (1.f / 128.f) - mean * mean, 0.f);
    float inv = rsqrtf(var + 1e-5f);
    float d = 0.f;
#pragma unroll
    for (int t = 0; t < 8; ++t) {
      int ch = t * 16 + cb;
      float4 gv = *(const float4*)(gamma + ch);
      float4 bt = *(const float4*)(beta + ch);
      float o0 = (vv[t][0] - mean) * inv * gv.x + bt.x;
      float o1 = (vv[t][1] - mean) * inv * gv.y + bt.y;
      float o2 = (vv[t][2] - mean) * inv * gv.z + bt.z;
      float o3 = (vv[t][3] - mean) * inv * gv.w + bt.w;
      if (!LAST) {
        __half2 p01 = __float22half2_rn(make_float2(o0, o1));
        __half2 p23 = __float22half2_rn(make_float2(o2, o3));
        *(uint2*)(hnew + (size_t)m * NH + ch) =
            make_uint2(*(unsigned*)&p01, *(unsigned*)&p23);
        int pv = 0;
        pv = __builtin_amdgcn_cvt_pk_fp8_f32(o0, o1, pv, 0);
        pv = __builtin_amdgcn_cvt_pk_fp8_f32(o2, o3, pv, 1);
        ((unsigned*)(h8out + (size_t)m * NH))[pdw(t, quad)] = (unsigned)pv;
      } else {
        float4 wv = *(const float4*)(Wout + ch);
        d += o0 * wv.x + o1 * wv.y + o2 * wv.z + o3 * wv.w;
      }
    }
    if (LAST) {
      d += __shfl_xor(d, 16, 64);
      d += __shfl_xor(d, 32, 64);
      dval = d;
      gnd = batch[m];
    }
  }

  if (LAST) {
    // in-block mean-pool: plain LDS writes, wave-0 broadcast reduce
    if (lane < 16)
      pool_s[wave * 16 + r16] =
          make_int2(active ? gnd : 0, __float_as_int(active ? dval : 0.f));
    __syncthreads();
    if (tid < 32) {
      float acc = 0.f;
#pragma unroll 8
      for (int k = 0; k < 128; ++k) {
        int2 e = pool_s[k];  // broadcast read
        if (e.x == tid) acc += __int_as_float(e.y);
      }
      atomicAdd(&gsum[tid], acc);
    }
    __threadfence();
    if (tid == 0) lastflag_s = (atomicAdd(done, 1) == (int)gridDim.x - 1);
    __syncthreads();
    if (lastflag_s && tid < NG) {
      float sv = atomicAdd(&gsum[tid], 0.f);
      int cv = 0;
      for (int b2 = 0; b2 < NB; ++b2) cv += gcnt_part[b2 * NG + tid];
      out[tid] = sv / fmaxf((float)cv, 1.0f);
    }
  }
}

extern "C" void kernel_launch(void* const* d_in, const int* in_sizes, int n_in,
                              void* d_out, int out_size, void* d_ws, size_t ws_size,
                              hipStream_t stream) {
  const float* x = (const float*)d_in[0];
  const int* eidx = (const int*)d_in[1];
  const int* batch = (const int*)d_in[2];
  const float* W_emb = (const float*)d_in[3];
  const float* b_emb = (const float*)d_in[4];
  const float* W_layers = (const float*)d_in[5];
  const float* b_layers = (const float*)d_in[6];
  const float* ln_gamma = (const float*)d_in[7];
  const float* ln_beta = (const float*)d_in[8];
  const float* W_out = (const float*)d_in[9];
  float* out = (float*)d_out;

  char* ws = (char*)d_ws;
  unsigned char* h8a = (unsigned char*)ws; ws += (size_t)NN * NH;  // fp8 trunk A
  unsigned char* h8b = (unsigned char*)ws; ws += (size_t)NN * NH;  // fp8 trunk B
  __half* h = (__half*)ws;      ws += (size_t)NN * NH * 2;         // fp16 trunk
  short* Whi = (short*)ws;      ws += (size_t)4 * WSLOT * 2;
  short* Wlo = (short*)ws;      ws += (size_t)4 * WSLOT * 2;
  float* dis = (float*)ws;      ws += (size_t)NN * 4;
  int2* csr = (int2*)ws;        ws += (size_t)NETOT * 8;
  int* rank = (int*)ws;         ws += (size_t)NE * 4;
  int* offs = (int*)ws;         ws += (size_t)NN * 4;
  int* deg = (int*)ws;          ws += (size_t)NN * 4;
  int* perm = (int*)ws;         ws += (size_t)NN * 4;
  int* bsum = (int*)ws;         ws += (size_t)NB * 4;
  int* bcnt = (int*)ws;         ws += (size_t)NB * 64 * 4;
  int* gcnt_part = (int*)ws;    ws += (size_t)NB * NG * 4;
  char* zero_base = ws;
  int* cnt4 = (int*)ws;         ws += (size_t)NN * 16;
  float* gsum = (float*)ws;     ws += (size_t)NG * 4;
  int* done = (int*)ws;         ws += 64;
  size_t zero_bytes = (size_t)(ws - zero_base);
  hipMemsetAsync(zero_base, 0, zero_bytes, stream);

  const int* erow = eidx;        // edge_index[0] = sources
  const int* ecol = eidx + NE;   // edge_index[1] = targets

  // K1: emb (self-staged W_emb) + hist + layer-W prep, one dispatch
  prep_hist_emb_kernel<<<EMBB + HISTB + PREP4B, 256, 0, stream>>>(
      x, W_emb, W_layers, Whi, Wlo, erow, ecol, cnt4, rank, b_emb, h, h8a);
  scan1_kernel<<<NB, 256, 0, stream>>>(cnt4, bsum, dis, deg, batch, gcnt_part,
                                       bcnt);
  scan3b_kernel<<<NB, 256, 0, stream>>>(deg, bsum, dis, offs, csr, bcnt, perm);
  fill_kernel<<<HISTB, 256, 0, stream>>>(erow, ecol, rank, cnt4, dis, offs, csr);

  int gblk = (NN + 127) / 128;
  for (int l = 0; l < NL; ++l) {
    const short* wh = Whi + (size_t)l * WSLOT;
    const short* wl = Wlo + (size_t)l * WSLOT;
    const float* bl = b_layers + (size_t)l * NH;
    const float* gl = ln_gamma + (size_t)l * NH;
    const float* be = ln_beta + (size_t)l * NH;
    const unsigned char* hin = (l & 1) ? h8b : h8a;
    unsigned char* hout = (l & 1) ? h8a : h8b;
    if (l == NL - 1)
      layer_fused<true><<<gblk, 512, 0, stream>>>(
          hin, wh, wl, bl, h, gl, be, W_out, offs, csr, perm, h, nullptr,
          batch, gsum, gcnt_part, done, out);
    else
      layer_fused<false><<<gblk, 512, 0, stream>>>(
          hin, wh, wl, bl, h, gl, be, nullptr, offs, csr, perm, h, hout,
          batch, gsum, gcnt_part, done, out);
  }
}

// Round 12
// 364.388 us; speedup vs baseline: 1.4647x; 1.0760x over previous
//
#include <hip/hip_runtime.h>
#include <hip/hip_fp16.h>

#define NN 50000   // nodes
#define NE 800000  // edges
#define NETOT (NE + NN)  // edges + self loops
#define NH 128     // hidden
#define NG 32      // graphs
#define NL 4       // layers
#define NB 196     // ceil(NN/256)
#define EMBB 782   // emb blocks (64 nodes each) in fused K1
#define HISTB 3125 // ceil(NE/256)
#define PREP4B 256 // 4*WSLOT/256 (W-prep for the 4 layer slots)
#define NTILE 12500 // source-tile width (4 tiles, 1.6 MB of fp8 trunk each)
#define WSLOT (NH * NH)  // 16384 elements per weight slot

typedef __attribute__((ext_vector_type(8))) short bf16x8;
typedef __attribute__((ext_vector_type(4))) float f32x4;
typedef __attribute__((ext_vector_type(2))) float f32x2;

__device__ inline short f2bf(float x) {
  union { float f; unsigned u; } v;
  v.f = x;
  unsigned r = v.u + 0x7FFF + ((v.u >> 16) & 1);
  return (short)(r >> 16);
}
__device__ inline float bf2f(short s) {
  union { unsigned u; float f; } v;
  v.u = ((unsigned)(unsigned short)s) << 16;
  return v.f;
}

// fp8 trunk layout (fragment-major, r1-r3 verified): channel ch = ks*32+quad*8+j
// stored at byte quad*32 + ks*8 + j -> per-lane gather reads its quad's 32
// contiguous bytes (2x uint4) per source row.
// Epilogue writes channels ch = t*16 + quad*4 + r; their dword index is:
__device__ inline int pdw(int t, int quad) {
  return (((2 * t + (quad >> 1)) & 3) << 3) + ((t >> 1) << 1) + (quad & 1);
}

// accumulate one fp8 row slice (2x uint4 = lane's 32 channels) into ag, * w
__device__ inline void fp8row_fma(float (&ag)[4][8], uint4 qa, uint4 qb,
                                  float w) {
  const unsigned dw[8] = {qa.x, qa.y, qa.z, qa.w, qb.x, qb.y, qb.z, qb.w};
#pragma unroll
  for (int ks = 0; ks < 4; ++ks) {
    f32x2 u0 = __builtin_amdgcn_cvt_pk_f32_fp8(dw[2 * ks], 0);
    f32x2 u1 = __builtin_amdgcn_cvt_pk_f32_fp8(dw[2 * ks], 1);
    f32x2 u2 = __builtin_amdgcn_cvt_pk_f32_fp8(dw[2 * ks + 1], 0);
    f32x2 u3 = __builtin_amdgcn_cvt_pk_f32_fp8(dw[2 * ks + 1], 1);
    ag[ks][0] += u0.x * w; ag[ks][1] += u0.y * w;
    ag[ks][2] += u1.x * w; ag[ks][3] += u1.y * w;
    ag[ks][4] += u2.x * w; ag[ks][5] += u2.y * w;
    ag[ks][6] += u3.x * w; ag[ks][7] += u3.y * w;
  }
}

// 256-thread block exclusive scan (wave shuffle + 4-wave combine)
__device__ inline int block_exscan(int v) {
  __shared__ int wsum[4];
  int tid = threadIdx.x, wave = tid >> 6, lane = tid & 63;
  int x = v;
#pragma unroll
  for (int off = 1; off < 64; off <<= 1) {
    int y = __shfl_up(x, off, 64);
    if (lane >= off) x += y;
  }
  if (lane == 63) wsum[wave] = x;
  __syncthreads();
  int wp = 0;
  if (wave > 0) wp += wsum[0];
  if (wave > 1) wp += wsum[1];
  if (wave > 2) wp += wsum[2];
  return wp + x - v;
}

// ---------------- K1 fused: emb GEMM (self-staged W) + hist + layer-W prep ---
__global__ __launch_bounds__(256) void prep_hist_emb_kernel(
    const float* __restrict__ Xf, const float* __restrict__ W_emb,
    const float* __restrict__ W_layers, short* __restrict__ hi,
    short* __restrict__ lo, const int* __restrict__ row,
    const int* __restrict__ col, int* __restrict__ cnt4, int* __restrict__ rank,
    const float* __restrict__ bias, __half* __restrict__ hnew,
    unsigned char* __restrict__ h8) {
  __shared__ short Wh[WSLOT];  // 32 KB (emb blocks only)
  __shared__ short Wl[WSLOT];  // 32 KB
  int tid = threadIdx.x;
  int blk = blockIdx.x;
  if (blk >= EMBB) {
    if (blk < EMBB + HISTB) {
      int e = (blk - EMBB) * 256 + tid;
      if (e < NE) {
        int s = row[e];
        int t = s / NTILE;  // 0..3
        rank[e] = atomicAdd(&cnt4[col[e] * 4 + t], 1);
      }
    } else {
      int i = (blk - EMBB - HISTB) * 256 + tid;
      if (i < 4 * WSLOT) {
        int slot = i >> 14, f = i & (WSLOT - 1);
        int j = f & 7, lane = (f >> 3) & 63, tt = (f >> 9) & 7, ks = f >> 12;
        int n = tt * 16 + (lane & 15);
        int k = ks * 32 + ((lane >> 4) & 3) * 8 + j;
        const float* W = W_layers + (size_t)slot * WSLOT;
        float x = W[n * NH + k];
        short hh = f2bf(x);
        hi[i] = hh;
        lo[i] = f2bf(x - bf2f(hh));
      }
    }
    return;
  }

  // ---- embedding block: self-stage W_emb into LDS in fragment order
#pragma unroll
  for (int i = tid * 8; i < WSLOT; i += 256 * 8) {
    int f = i;
    int lane8 = (f >> 3) & 63, tt = (f >> 9) & 7, ks = f >> 12;
    int n = tt * 16 + (lane8 & 15);
    int k0 = ks * 32 + ((lane8 >> 4) & 3) * 8;
    const float* wr = W_emb + n * NH + k0;
    float4 a0 = *(const float4*)wr;
    float4 a1 = *(const float4*)(wr + 4);
    float wv[8] = {a0.x, a0.y, a0.z, a0.w, a1.x, a1.y, a1.z, a1.w};
    bf16x8 vh, vl;
#pragma unroll
    for (int j = 0; j < 8; ++j) {
      short hh = f2bf(wv[j]);
      vh[j] = hh;
      vl[j] = f2bf(wv[j] - bf2f(hh));
    }
    *(bf16x8*)&Wh[i] = vh;
    *(bf16x8*)&Wl[i] = vl;
  }
  __syncthreads();

  int wave = tid >> 6, lane = tid & 63;
  int quad = lane >> 4, r16 = lane & 15;
  int m0 = blk * 64 + wave * 16;
  if (m0 >= NN) return;
  int mA = m0 + r16;

  f32x4 acc[8];
#pragma unroll
  for (int t = 0; t < 8; ++t) acc[t] = (f32x4){0.f, 0.f, 0.f, 0.f};

#pragma unroll
  for (int ks = 0; ks < 4; ++ks) {
    int klane = ks * 32 + quad * 8;
    const float* xr = Xf + (size_t)mA * NH + klane;
    float4 a0 = *(const float4*)xr;
    float4 a1 = *(const float4*)(xr + 4);
    float af[8] = {a0.x, a0.y, a0.z, a0.w, a1.x, a1.y, a1.z, a1.w};
    bf16x8 xhi, xlo;
#pragma unroll
    for (int j = 0; j < 8; ++j) {
      short h = f2bf(af[j]);
      xhi[j] = h;
      xlo[j] = f2bf(af[j] - bf2f(h));
    }
#pragma unroll
    for (int t = 0; t < 8; ++t) {
      int fidx = ((ks * 8 + t) * 64 + lane) << 3;
      bf16x8 whi = *(const bf16x8*)&Wh[fidx];
      bf16x8 wlo = *(const bf16x8*)&Wl[fidx];
      acc[t] = __builtin_amdgcn_mfma_f32_16x16x32_bf16(whi, xhi, acc[t], 0, 0, 0);
      acc[t] = __builtin_amdgcn_mfma_f32_16x16x32_bf16(whi, xlo, acc[t], 0, 0, 0);
      acc[t] = __builtin_amdgcn_mfma_f32_16x16x32_bf16(wlo, xhi, acc[t], 0, 0, 0);
    }
  }

  int m = m0 + r16;
  int cb = quad * 4;
#pragma unroll
  for (int t = 0; t < 8; ++t) {
    int ch = t * 16 + cb;
    float4 bb = *(const float4*)(bias + ch);
    float o0 = acc[t][0] + bb.x, o1 = acc[t][1] + bb.y;
    float o2 = acc[t][2] + bb.z, o3 = acc[t][3] + bb.w;
    __half2 p01 = __float22half2_rn(make_float2(o0, o1));
    __half2 p23 = __float22half2_rn(make_float2(o2, o3));
    *(uint2*)(hnew + (size_t)m * NH + ch) =
        make_uint2(*(unsigned*)&p01, *(unsigned*)&p23);
    int v = 0;
    v = __builtin_amdgcn_cvt_pk_fp8_f32(o0, o1, v, 0);
    v = __builtin_amdgcn_cvt_pk_fp8_f32(o2, o3, v, 1);
    ((unsigned*)(h8 + (size_t)m * NH))[pdw(t, quad)] = (unsigned)v;
  }
}

// ---------------- scan stage 1: deg' = cnt+1, dis, per-block graph counts ----
// NO global atomics: per-block graph counts are written as plain arrays
// (gcnt_part[b][32]) and summed at finalize.
__global__ __launch_bounds__(256) void scan1_kernel(
    const int* __restrict__ cnt4, int* __restrict__ bsum,
    float* __restrict__ dis, int* __restrict__ deg,
    const int* __restrict__ batch, int* __restrict__ gcnt_part) {
  __shared__ int gbins[NG];
  __shared__ int ws[4];
  int tid = threadIdx.x;
  if (tid < NG) gbins[tid] = 0;
  __syncthreads();
  int i = blockIdx.x * 256 + tid;
  int v = 0;
  if (i < NN) {
    int4 c4 = *(const int4*)&cnt4[i * 4];
    v = c4.x + c4.y + c4.z + c4.w + 1;  // + self loop
    deg[i] = v;
    dis[i] = rsqrtf((float)v);
    atomicAdd(&gbins[batch[i]], 1);    // native LDS int atomic
  }
  int lane = tid & 63;
  int s = v;
#pragma unroll
  for (int off = 32; off; off >>= 1) s += __shfl_down(s, off, 64);
  if (lane == 0) ws[tid >> 6] = s;
  __syncthreads();
  if (tid == 0) bsum[blockIdx.x] = ws[0] + ws[1] + ws[2] + ws[3];
  if (tid < NG) gcnt_part[blockIdx.x * NG + tid] = gbins[tid];
}

// ---------------- scan stage 2+3 fused + self-edge emit ----------------------
__global__ __launch_bounds__(256) void scan3b_kernel(const int* __restrict__ deg,
                                                     const int* __restrict__ bsum,
                                                     const float* __restrict__ dis,
                                                     int* __restrict__ offs,
                                                     int2* __restrict__ csr) {
  __shared__ int ws2[4];
  int tid = threadIdx.x;
  int b = blockIdx.x;
  int v = (tid < NB && tid < b) ? bsum[tid] : 0;
  int lane = tid & 63;
  int s = v;
#pragma unroll
  for (int off = 32; off; off >>= 1) s += __shfl_down(s, off, 64);
  if (lane == 0) ws2[tid >> 6] = s;
  __syncthreads();
  int bo = ws2[0] + ws2[1] + ws2[2] + ws2[3];
  int i = b * 256 + tid;
  int c = (i < NN) ? deg[i] : 0;
  int ex = block_exscan(c);
  if (i < NN) {
    int o = bo + ex;
    offs[i] = o;
    // self edge at the last slot: x = (src<<6)|tl, y = fp32 weight dis^2
    float dii = dis[i];
    csr[o + c - 1] =
        make_int2((i << 6) | (i & 63), __float_as_int(dii * dii));
  }
}

// ---------------- CSR fill: slot = offs[d] + tile-prefix + rank --------------
__global__ __launch_bounds__(256) void fill_kernel(const int* __restrict__ row,
                                                   const int* __restrict__ col,
                                                   const int* __restrict__ rank,
                                                   const int* __restrict__ cnt4,
                                                   const float* __restrict__ dis,
                                                   const int* __restrict__ offs,
                                                   int2* __restrict__ csr) {
  int e = blockIdx.x * 256 + threadIdx.x;
  if (e < NE) {
    int d = col[e];
    int s = row[e];
    int t = s / NTILE;
    int4 c4 = *(const int4*)&cnt4[d * 4];
    int pre = (t > 0 ? c4.x : 0) + (t > 1 ? c4.y : 0) + (t > 2 ? c4.z : 0);
    int pos = offs[d] + pre + rank[e];
    csr[pos] =
        make_int2((s << 6) | (d & 63), __float_as_int(dis[s] * dis[d]));
  }
}

// ---------------- fused layer (r3/r9 structure): per-lane gather + LDS W -----
// 512 threads / 128 consecutive nodes per block (node-contiguous: coalesced
// hprev/hnew/h8 and clustered CSR windows — r11 proved perm-scatter costs 2.4x).
// Lane (quad, r16) owns node m0+r16, slice quad*32; walks its node's
// tile-grouped CSR run (self-edge included) 2-wide. hprev hoisted before the
// gather. LAST layer mean-pools in-block (plain LDS + broadcast reduce +
// done-counter finalize with gcnt_part sum).
template <bool LAST>
__global__ __launch_bounds__(512) void layer_fused(
    const unsigned char* __restrict__ h8in, const short* __restrict__ Whi,
    const short* __restrict__ Wlo, const float* __restrict__ bias,
    const __half* __restrict__ hprev, const float* __restrict__ gamma,
    const float* __restrict__ beta, const float* __restrict__ Wout,
    const int* __restrict__ offs, const int2* __restrict__ csr,
    __half* __restrict__ hnew, unsigned char* __restrict__ h8out,
    const int* __restrict__ batch, float* __restrict__ gsum,
    const int* __restrict__ gcnt_part, int* __restrict__ done,
    float* __restrict__ out) {
  __shared__ short Wh[WSLOT];  // 32 KB
  __shared__ short Wl[WSLOT];  // 32 KB
  __shared__ int2 pool_s[128];
  __shared__ int lastflag_s;
  int tid = threadIdx.x;
#pragma unroll
  for (int i = tid * 8; i < WSLOT; i += 512 * 8) {
    *(bf16x8*)&Wh[i] = *(const bf16x8*)(Whi + i);
    *(bf16x8*)&Wl[i] = *(const bf16x8*)(Wlo + i);
  }
  // no barrier yet: gather overlaps the LDS staging latency

  int wave = tid >> 6, lane = tid & 63;
  int quad = lane >> 4, r16 = lane & 15;
  int m0 = blockIdx.x * 128 + wave * 16;
  bool active = m0 < NN;        // wave-uniform; inactive waves still barrier
  int nd = active ? m0 + r16 : 0;
  int cb = quad * 4;

  // early hprev load: in flight during the whole gather
  uint2 hp[8];
#pragma unroll
  for (int t = 0; t < 8; ++t)
    hp[t] = *(const uint2*)(hprev + (size_t)nd * NH + t * 16 + cb);

  float ag[4][8];
#pragma unroll
  for (int ks = 0; ks < 4; ++ks)
#pragma unroll
    for (int j = 0; j < 8; ++j) ag[ks][j] = 0.f;

  const char* rbase = (const char*)h8in + quad * 32;
  int s0 = offs[nd];
  int e1 = active ? ((nd + 1 < NN) ? offs[nd + 1] : NETOT) : s0;
  int j = s0;
  for (; j + 2 <= e1; j += 2) {
    int2 p0 = csr[j], p1 = csr[j + 1];
    const uint4* r0 = (const uint4*)(rbase + (size_t)(((unsigned)p0.x) >> 6) * NH);
    const uint4* r1 = (const uint4*)(rbase + (size_t)(((unsigned)p1.x) >> 6) * NH);
    uint4 a0 = r0[0], b0 = r0[1];
    uint4 a1 = r1[0], b1 = r1[1];
    fp8row_fma(ag, a0, b0, __int_as_float(p0.y));
    fp8row_fma(ag, a1, b1, __int_as_float(p1.y));
  }
  if (j < e1) {
    int2 p0 = csr[j];
    const uint4* r0 = (const uint4*)(rbase + (size_t)(((unsigned)p0.x) >> 6) * NH);
    uint4 a0 = r0[0], b0 = r0[1];
    fp8row_fma(ag, a0, b0, __int_as_float(p0.y));
  }

  __syncthreads();  // W staging complete; all waves participate

  if (!LAST) {
    if (!active) return;
  }

  float dval = 0.f;
  int gnd = 0;
  if (active) {
    f32x4 acc[8];
#pragma unroll
    for (int t = 0; t < 8; ++t) acc[t] = (f32x4){0.f, 0.f, 0.f, 0.f};

#pragma unroll
    for (int ks = 0; ks < 4; ++ks) {
      bf16x8 xhi, xlo;
#pragma unroll
      for (int q = 0; q < 8; ++q) {
        short hh = f2bf(ag[ks][q]);
        xhi[q] = hh;
        xlo[q] = f2bf(ag[ks][q] - bf2f(hh));
      }
#pragma unroll
      for (int t = 0; t < 8; ++t) {
        int fidx = ((ks * 8 + t) * 64 + lane) << 3;
        bf16x8 whi = *(const bf16x8*)&Wh[fidx];
        bf16x8 wlo = *(const bf16x8*)&Wl[fidx];
        acc[t] = __builtin_amdgcn_mfma_f32_16x16x32_bf16(whi, xhi, acc[t], 0, 0, 0);
        acc[t] = __builtin_amdgcn_mfma_f32_16x16x32_bf16(whi, xlo, acc[t], 0, 0, 0);
        acc[t] = __builtin_amdgcn_mfma_f32_16x16x32_bf16(wlo, xhi, acc[t], 0, 0, 0);
      }
    }

    // ---- epilogue: lane owns node m = nd, channels ch = t*16 + quad*4 + r
    int m = nd;
    float vv[8][4];
    float s = 0.f, s2 = 0.f;
#pragma unroll
    for (int t = 0; t < 8; ++t) {
      int ch = t * 16 + cb;
      float4 bb = *(const float4*)(bias + ch);
      float2 h01 = __half22float2(*(__half2*)&hp[t].x);
      float2 h23 = __half22float2(*(__half2*)&hp[t].y);
      float hv[4] = {h01.x, h01.y, h23.x, h23.y};
      float bb4[4] = {bb.x, bb.y, bb.z, bb.w};
#pragma unroll
      for (int r = 0; r < 4; ++r) {
        float z = fmaxf(acc[t][r] + bb4[r], 0.f);
        float val = hv[r] + z;
        vv[t][r] = val;
        s += val;
        s2 += val * val;
      }
    }
    s += __shfl_xor(s, 16, 64);
    s += __shfl_xor(s, 32, 64);
    s2 += __shfl_xor(s2, 16, 64);
    s2 += __shfl_xor(s2, 32, 64);
    float mean = s * (1.f / 128.f);
    float var = fmaxf(s2 * (1.f / 128.f) - mean * mean, 0.f);
    float inv = rsqrtf(var + 1e-5f);
    float d = 0.f;
#pragma unroll
    for (int t = 0; t < 8; ++t) {
      int ch = t * 16 + cb;
      float4 gv = *(const float4*)(gamma + ch);
      float4 bt = *(const float4*)(beta + ch);
      float o0 = (vv[t][0] - mean) * inv * gv.x + bt.x;
      float o1 = (vv[t][1] - mean) * inv * gv.y + bt.y;
      float o2 = (vv[t][2] - mean) * inv * gv.z + bt.z;
      float o3 = (vv[t][3] - mean) * inv * gv.w + bt.w;
      if (!LAST) {
        __half2 p01 = __float22half2_rn(make_float2(o0, o1));
        __half2 p23 = __float22half2_rn(make_float2(o2, o3));
        *(uint2*)(hnew + (size_t)m * NH + ch) =
            make_uint2(*(unsigned*)&p01, *(unsigned*)&p23);
        int pv = 0;
        pv = __builtin_amdgcn_cvt_pk_fp8_f32(o0, o1, pv, 0);
        pv = __builtin_amdgcn_cvt_pk_fp8_f32(o2, o3, pv, 1);
        ((unsigned*)(h8out + (size_t)m * NH))[pdw(t, quad)] = (unsigned)pv;
      } else {
        float4 wv = *(const float4*)(Wout + ch);
        d += o0 * wv.x + o1 * wv.y + o2 * wv.z + o3 * wv.w;
      }
    }
    if (LAST) {
      d += __shfl_xor(d, 16, 64);
      d += __shfl_xor(d, 32, 64);
      dval = d;
      gnd = batch[m];
    }
  }

  if (LAST) {
    // in-block mean-pool: plain LDS writes, wave-0 broadcast reduce
    if (lane < 16)
      pool_s[wave * 16 + r16] =
          make_int2(active ? gnd : 0, __float_as_int(active ? dval : 0.f));
    __syncthreads();
    if (tid < 32) {
      float acc = 0.f;
#pragma unroll 8
      for (int k = 0; k < 128; ++k) {
        int2 e = pool_s[k];  // broadcast read
        if (e.x == tid) acc += __int_as_float(e.y);
      }
      atomicAdd(&gsum[tid], acc);
    }
    __threadfence();
    if (tid == 0) lastflag_s = (atomicAdd(done, 1) == (int)gridDim.x - 1);
    __syncthreads();
    if (lastflag_s && tid < NG) {
      float sv = atomicAdd(&gsum[tid], 0.f);
      int cv = 0;
      for (int b2 = 0; b2 < NB; ++b2) cv += gcnt_part[b2 * NG + tid];
      out[tid] = sv / fmaxf((float)cv, 1.0f);
    }
  }
}

extern "C" void kernel_launch(void* const* d_in, const int* in_sizes, int n_in,
                              void* d_out, int out_size, void* d_ws, size_t ws_size,
                              hipStream_t stream) {
  const float* x = (const float*)d_in[0];
  const int* eidx = (const int*)d_in[1];
  const int* batch = (const int*)d_in[2];
  const float* W_emb = (const float*)d_in[3];
  const float* b_emb = (const float*)d_in[4];
  const float* W_layers = (const float*)d_in[5];
  const float* b_layers = (const float*)d_in[6];
  const float* ln_gamma = (const float*)d_in[7];
  const float* ln_beta = (const float*)d_in[8];
  const float* W_out = (const float*)d_in[9];
  float* out = (float*)d_out;

  char* ws = (char*)d_ws;
  unsigned char* h8a = (unsigned char*)ws; ws += (size_t)NN * NH;  // fp8 trunk A
  unsigned char* h8b = (unsigned char*)ws; ws += (size_t)NN * NH;  // fp8 trunk B
  __half* h = (__half*)ws;      ws += (size_t)NN * NH * 2;         // fp16 trunk
  short* Whi = (short*)ws;      ws += (size_t)4 * WSLOT * 2;
  short* Wlo = (short*)ws;      ws += (size_t)4 * WSLOT * 2;
  float* dis = (float*)ws;      ws += (size_t)NN * 4;
  int2* csr = (int2*)ws;        ws += (size_t)NETOT * 8;
  int* rank = (int*)ws;         ws += (size_t)NE * 4;
  int* offs = (int*)ws;         ws += (size_t)NN * 4;
  int* deg = (int*)ws;          ws += (size_t)NN * 4;
  int* bsum = (int*)ws;         ws += (size_t)NB * 4;
  int* gcnt_part = (int*)ws;    ws += (size_t)NB * NG * 4;
  char* zero_base = ws;
  int* cnt4 = (int*)ws;         ws += (size_t)NN * 16;
  float* gsum = (float*)ws;     ws += (size_t)NG * 4;
  int* done = (int*)ws;         ws += 64;
  size_t zero_bytes = (size_t)(ws - zero_base);
  hipMemsetAsync(zero_base, 0, zero_bytes, stream);

  const int* erow = eidx;        // edge_index[0] = sources
  const int* ecol = eidx + NE;   // edge_index[1] = targets

  // K1: emb (self-staged W_emb) + hist + layer-W prep, one dispatch
  prep_hist_emb_kernel<<<EMBB + HISTB + PREP4B, 256, 0, stream>>>(
      x, W_emb, W_layers, Whi, Wlo, erow, ecol, cnt4, rank, b_emb, h, h8a);
  scan1_kernel<<<NB, 256, 0, stream>>>(cnt4, bsum, dis, deg, batch, gcnt_part);
  scan3b_kernel<<<NB, 256, 0, stream>>>(deg, bsum, dis, offs, csr);
  fill_kernel<<<HISTB, 256, 0, stream>>>(erow, ecol, rank, cnt4, dis, offs, csr);

  int gblk = (NN + 127) / 128;
  for (int l = 0; l < NL; ++l) {
    const short* wh = Whi + (size_t)l * WSLOT;
    const short* wl = Wlo + (size_t)l * WSLOT;
    const float* bl = b_layers + (size_t)l * NH;
    const float* gl = ln_gamma + (size_t)l * NH;
    const float* be = ln_beta + (size_t)l * NH;
    const unsigned char* hin = (l & 1) ? h8b : h8a;
    unsigned char* hout = (l & 1) ? h8a : h8b;
    if (l == NL - 1)
      layer_fused<true><<<gblk, 512, 0, stream>>>(
          hin, wh, wl, bl, h, gl, be, W_out, offs, csr, h, nullptr, batch,
          gsum, gcnt_part, done, out);
    else
      layer_fused<false><<<gblk, 512, 0, stream>>>(
          hin, wh, wl, bl, h, gl, be, nullptr, offs, csr, h, hout, batch,
          gsum, gcnt_part, done, out);
  }
}